// Round 13
// baseline (66.014 us; speedup 1.0000x reference)
//
#include <hip/hip_runtime.h>

// EdgeClassifier:
//   Hd = q8(zd @ W1[:, :128]^T + b1), per-row scale, biased uint8
//   Hp = q8(zp @ W1[:, 128:]^T),      per-row scale, biased uint8
//   out[e] = W2 . relu(Hd[row]*sd + Hp[col]*sp) + b2
// R13: edge = exact R10 (best measured ~37.8us). hprep = R10 structure with
//      32-row tiles @ 256 threads (tail shrinks: 3126 blocks, ~2048 resident).

typedef __attribute__((ext_vector_type(8))) short bhalf8;
typedef __attribute__((ext_vector_type(4))) float f32x4;
typedef _Float16 half2_t __attribute__((ext_vector_type(2)));

__device__ __forceinline__ unsigned bfr(float f) {
    unsigned u = __builtin_bit_cast(unsigned, f);
    return (u + 0x7fffu + ((u >> 16) & 1u)) >> 16;
}
__device__ __forceinline__ unsigned pk2(float a, float b) {
    return bfr(a) | (bfr(b) << 16);
}

#define SH_STRIDE 132   // fp32 elems; 528B rows: 16B-aligned, <=4-way LDS conflicts

// ---------- K1: H-prep GEMM + per-row quantize, 32-row tiles / 256 threads ----------
// 4 waves; wave w owns cols w*32..w*32+31 (2 col-tiles); 2 row-tiles of 16.
__global__ __launch_bounds__(256) void hprepq_kernel(
    const float* __restrict__ zd, const float* __restrict__ zp,
    const float* __restrict__ W1, const float* __restrict__ b1,
    unsigned char* __restrict__ Hd, unsigned char* __restrict__ Hp,
    float* __restrict__ scD, float* __restrict__ scP,
    int Nd, int Np, int nbd)
{
    __shared__ __align__(16) char smem[32 * SH_STRIDE * 4];   // 16.9 KB
    short* sZ = (short*)smem;          // staging view (8 KB bf16, XOR-swizzled)
    float* sH = (float*)smem;          // h-transpose view (stride SH_STRIDE)

    const bool isP = (int)blockIdx.x >= nbd;
    const float* z = isP ? zp : zd;
    unsigned char* H = isP ? Hp : Hd;
    float* sc = isP ? scP : scD;
    const int N    = isP ? Np : Nd;
    const int koff = isP ? 128 : 0;
    const int blk  = isP ? blockIdx.x - nbd : blockIdx.x;

    const int tid  = threadIdx.x;
    const int w    = tid >> 6;         // wave 0..3
    const int lane = tid & 63;
    const int l15  = lane & 15;
    const int lhi  = lane >> 4;

    // B-fragments for 2 col-tiles: lane holds W1[ocol][koff + ks*32 + lhi*8 + i]
    bhalf8 bfrag[2][4];
    float biasv[2];
    #pragma unroll
    for (int ct = 0; ct < 2; ++ct) {
        const int ocol = w * 32 + ct * 16 + l15;
        #pragma unroll
        for (int ks = 0; ks < 4; ++ks) {
            const float4* src = (const float4*)(W1 + ocol * 256 + koff + ks * 32 + lhi * 8);
            float4 p = src[0], q = src[1];
            bhalf8 f;
            f[0] = (short)bfr(p.x); f[1] = (short)bfr(p.y);
            f[2] = (short)bfr(p.z); f[3] = (short)bfr(p.w);
            f[4] = (short)bfr(q.x); f[5] = (short)bfr(q.y);
            f[6] = (short)bfr(q.z); f[7] = (short)bfr(q.w);
            bfrag[ct][ks] = f;
        }
        biasv[ct] = isP ? 0.0f : b1[ocol];
    }
    const int r0 = blk * 32;

    // stage 32 rows x 128 fp32 -> bf16 LDS (8 threads/row, 4 x float4 each)
    {
        const int rl = tid >> 3;                 // 0..31
        const int grow = min(r0 + rl, N - 1);
        const float4* zr = (const float4*)(z + (size_t)grow * 128);
        #pragma unroll
        for (int q = 0; q < 4; ++q) {
            const int s = (tid & 7) + q * 8;     // 8B chunk index 0..31
            float4 v = zr[s];
            uint2 ww; ww.x = pk2(v.x, v.y); ww.y = pk2(v.z, v.w);
            int byte = (rl * 256 + s * 8) ^ ((rl & 7) << 4);
            *(uint2*)((char*)sZ + byte) = ww;
        }
    }
    __syncthreads();

    f32x4 acc[2][2];
    #pragma unroll
    for (int ct = 0; ct < 2; ++ct)
        #pragma unroll
        for (int rt = 0; rt < 2; ++rt) acc[ct][rt] = (f32x4){0.f, 0.f, 0.f, 0.f};

    #pragma unroll
    for (int ks = 0; ks < 4; ++ks) {
        #pragma unroll
        for (int rt = 0; rt < 2; ++rt) {
            const int row = rt * 16 + l15;
            int byte = (row * 256 + ks * 64 + lhi * 16) ^ ((row & 7) << 4);
            bhalf8 af = *(const bhalf8*)((const char*)sZ + byte);
            #pragma unroll
            for (int ct = 0; ct < 2; ++ct)
                acc[ct][rt] = __builtin_amdgcn_mfma_f32_16x16x32_bf16(af, bfrag[ct][ks], acc[ct][rt], 0, 0, 0);
        }
    }
    __syncthreads();   // done reading sZ; smem becomes sH

    // transpose h into LDS: sH[row][col], stride SH_STRIDE
    #pragma unroll
    for (int ct = 0; ct < 2; ++ct) {
        const int ocol = w * 32 + ct * 16 + l15;
        #pragma unroll
        for (int rt = 0; rt < 2; ++rt)
            #pragma unroll
            for (int i = 0; i < 4; ++i) {
                const int row = rt * 16 + lhi * 4 + i;
                sH[row * SH_STRIDE + ocol] = acc[ct][rt][i] + biasv[ct];
            }
    }
    __syncthreads();

    // per-row absmax + quantize: 8 threads/row, 16 cols each (R10-proven epilogue)
    {
        const int qrow = tid >> 3;               // 0..31
        const int k    = tid & 7;
        float4 v4[4];
        float mx = 0.0f;
        #pragma unroll
        for (int j = 0; j < 4; ++j) {
            v4[j] = *(const float4*)(sH + qrow * SH_STRIDE + k * 16 + j * 4);
            mx = fmaxf(mx, fmaxf(fmaxf(fabsf(v4[j].x), fabsf(v4[j].y)),
                                 fmaxf(fabsf(v4[j].z), fabsf(v4[j].w))));
        }
        mx = fmaxf(mx, __shfl_xor(mx, 1, 64));
        mx = fmaxf(mx, __shfl_xor(mx, 2, 64));
        mx = fmaxf(mx, __shfl_xor(mx, 4, 64));
        const float inv = 127.0f / fmaxf(mx, 1e-20f);
        uint4 o;
        unsigned ob[4];
        #pragma unroll
        for (int j = 0; j < 4; ++j) {
            int a0 = __float2int_rn(v4[j].x * inv);
            int a1 = __float2int_rn(v4[j].y * inv);
            int a2 = __float2int_rn(v4[j].z * inv);
            int a3 = __float2int_rn(v4[j].w * inv);
            ob[j] = ((unsigned)(a0 & 0xff) | ((unsigned)(a1 & 0xff) << 8) |
                     ((unsigned)(a2 & 0xff) << 16) | ((unsigned)(a3 & 0xff) << 24))
                    ^ 0x80808080u;               // bias to uint8
        }
        o.x = ob[0]; o.y = ob[1]; o.z = ob[2]; o.w = ob[3];
        const int grow = r0 + qrow;
        if (grow < N) {
            *(uint4*)(H + (size_t)grow * 128 + k * 16) = o;
            if (k == 0) sc[grow] = mx * (1.0f / 127.0f);
        }
    }
}

// ---------- K2: per-edge gather + packed-f16 dequant/relu/dot (R10 exact) ----------
// 8 lanes/edge, uint4 per lane per table; 4 edges/group/iter
__global__ __launch_bounds__(256, 4) void edgeq_kernel(
    const unsigned char* __restrict__ Hd, const unsigned char* __restrict__ Hp,
    const float* __restrict__ scD, const float* __restrict__ scP,
    const int* __restrict__ eli, const float* __restrict__ W2,
    const float* __restrict__ b2, float* __restrict__ out, int E)
{
    const int sub = threadIdx.x & 7;
    const int grp = threadIdx.x >> 3;                // 0..31
    half2_t w2h[8];
    #pragma unroll
    for (int j = 0; j < 8; ++j) {
        float2 ww = ((const float2*)W2)[sub * 8 + j];
        w2h[j][0] = (_Float16)ww.x; w2h[j][1] = (_Float16)ww.y;
    }
    const float b2v = b2[0];
    const half2_t c1152 = { (_Float16)1152.0f, (_Float16)1152.0f };

    const int EPB = 32 * 4;                          // 128 edges per block-iter
    const int step = gridDim.x * EPB;
    int base = blockIdx.x * EPB;
    if (base >= E) return;

    int row[4], col[4];
    #pragma unroll
    for (int u = 0; u < 4; ++u) {
        const int e = base + grp * 4 + u;
        row[u] = (e < E) ? eli[e] : 0;
        col[u] = (e < E) ? eli[E + e] : 0;
    }

    for (; base < E; base += step) {
        uint4 qd[4], qp[4];
        float sdc[4], r[4];
        #pragma unroll
        for (int u = 0; u < 4; ++u) {
            qd[u] = *(const uint4*)(Hd + (size_t)row[u] * 128 + sub * 16);
            qp[u] = *(const uint4*)(Hp + (size_t)col[u] * 128 + sub * 16);
            const float sd = scD[row[u]];
            const float sp = scP[col[u]];
            sdc[u] = fmaxf(sd, 1e-25f);
            r[u]   = sp * __builtin_amdgcn_rcpf(sdc[u]);
        }
        const int nb = base + step;
        if (nb < E) {
            #pragma unroll
            for (int u = 0; u < 4; ++u) {
                const int e = nb + grp * 4 + u;
                row[u] = (e < E) ? eli[e] : 0;
                col[u] = (e < E) ? eli[E + e] : 0;
            }
        }
        #pragma unroll
        for (int u = 0; u < 4; ++u) {
            const _Float16 rh = (_Float16)r[u];
            const half2_t ru2 = { rh, rh };
            float s = 0.f;
            const unsigned dws[4] = {qd[u].x, qd[u].y, qd[u].z, qd[u].w};
            const unsigned pws[4] = {qp[u].x, qp[u].y, qp[u].z, qp[u].w};
            #pragma unroll
            for (int j = 0; j < 4; ++j) {
                const unsigned dw = dws[j], pw = pws[j];
                half2_t d0 = __builtin_bit_cast(half2_t,
                    __builtin_amdgcn_perm(0x64646464u, dw, 0x04010400u)) - c1152;
                half2_t d1 = __builtin_bit_cast(half2_t,
                    __builtin_amdgcn_perm(0x64646464u, dw, 0x04030402u)) - c1152;
                half2_t p0 = __builtin_bit_cast(half2_t,
                    __builtin_amdgcn_perm(0x64646464u, pw, 0x04010400u)) - c1152;
                half2_t p1 = __builtin_bit_cast(half2_t,
                    __builtin_amdgcn_perm(0x64646464u, pw, 0x04030402u)) - c1152;
                half2_t t0 = __builtin_elementwise_max(
                    __builtin_elementwise_fma(ru2, p0, d0), (half2_t){0, 0});
                half2_t t1 = __builtin_elementwise_max(
                    __builtin_elementwise_fma(ru2, p1, d1), (half2_t){0, 0});
                s = __builtin_amdgcn_fdot2(t0, w2h[j * 2],     s, false);
                s = __builtin_amdgcn_fdot2(t1, w2h[j * 2 + 1], s, false);
            }
            s += __shfl_xor(s, 1, 64);
            s += __shfl_xor(s, 2, 64);
            s += __shfl_xor(s, 4, 64);
            const int e = base + grp * 4 + u;
            if (sub == 0 && e < E) out[e] = fmaf(s, sdc[u], b2v);
        }
    }
}

// ---------- last-resort fallback: proven R1 kernel ----------
#define TE 64
__global__ __launch_bounds__(512, 4) void ec_fallback(
    const float* __restrict__ zd, const float* __restrict__ zp,
    const int* __restrict__ eli, const float* __restrict__ W1,
    const float* __restrict__ b1, const float* __restrict__ W2,
    const float* __restrict__ b2, float* __restrict__ out,
    int E, int nTiles)
{
    __shared__ __align__(16) short sZ[TE * 256];
    __shared__ float sPart[8][TE];
    const int tid  = threadIdx.x;
    const int wave = tid >> 6;
    const int lane = tid & 63;
    const int l15  = lane & 15;
    const int lhi  = lane >> 4;
    const int ocol = wave * 16 + l15;
    bhalf8 bfrag[8];
    #pragma unroll
    for (int ks = 0; ks < 8; ++ks) {
        const float4* src = (const float4*)(W1 + ocol * 256 + ks * 32 + lhi * 8);
        float4 p = src[0], q = src[1];
        bhalf8 f;
        f[0] = (short)bfr(p.x); f[1] = (short)bfr(p.y);
        f[2] = (short)bfr(p.z); f[3] = (short)bfr(p.w);
        f[4] = (short)bfr(q.x); f[5] = (short)bfr(q.y);
        f[6] = (short)bfr(q.z); f[7] = (short)bfr(q.w);
        bfrag[ks] = f;
    }
    const float b1v = b1[ocol];
    const float w2v = W2[ocol];
    const float b2v = b2[0];
    const int slot = tid >> 5;
    const int lane32 = tid & 31;
    for (int tile = blockIdx.x; tile < nTiles; tile += gridDim.x) {
        const int base = tile * TE;
        __syncthreads();
        #pragma unroll
        for (int r = 0; r < 4; ++r) {
            const int e  = slot * 4 + r;
            const int eg = base + e;
            int drow = 0, pcol = 0;
            if (eg < E) { drow = eli[eg]; pcol = eli[E + eg]; }
            float4 v = ((const float4*)(zd + (size_t)drow * 128))[lane32];
            float4 u = ((const float4*)(zp + (size_t)pcol * 128))[lane32];
            int byte0 = (e * 512 + lane32 * 8) ^ ((e & 7) << 4);
            uint2 pv; pv.x = pk2(v.x, v.y); pv.y = pk2(v.z, v.w);
            *(uint2*)((char*)sZ + byte0) = pv;
            int byte1 = (e * 512 + 256 + lane32 * 8) ^ ((e & 7) << 4);
            uint2 pu; pu.x = pk2(u.x, u.y); pu.y = pk2(u.z, u.w);
            *(uint2*)((char*)sZ + byte1) = pu;
        }
        __syncthreads();
        f32x4 acc[4] = {{0.f,0.f,0.f,0.f},{0.f,0.f,0.f,0.f},
                        {0.f,0.f,0.f,0.f},{0.f,0.f,0.f,0.f}};
        #pragma unroll
        for (int ks = 0; ks < 8; ++ks) {
            const int kb = (ks * 32 + lhi * 8) * 2;
            #pragma unroll
            for (int rt = 0; rt < 4; ++rt) {
                const int row = rt * 16 + l15;
                int byte = (row * 512 + kb) ^ ((row & 7) << 4);
                bhalf8 af = *(const bhalf8*)((const char*)sZ + byte);
                acc[rt] = __builtin_amdgcn_mfma_f32_16x16x32_bf16(af, bfrag[ks], acc[rt], 0, 0, 0);
            }
        }
        #pragma unroll
        for (int rt = 0; rt < 4; ++rt) {
            #pragma unroll
            for (int i = 0; i < 4; ++i) {
                float v = acc[rt][i] + b1v;
                v = fmaxf(v, 0.0f) * w2v;
                v += __shfl_xor(v, 1, 64);
                v += __shfl_xor(v, 2, 64);
                v += __shfl_xor(v, 4, 64);
                v += __shfl_xor(v, 8, 64);
                if (l15 == 0) sPart[wave][rt * 16 + lhi * 4 + i] = v;
            }
        }
        __syncthreads();
        if (tid < TE) {
            const int eg = base + tid;
            if (eg < E) {
                float s = b2v;
                #pragma unroll
                for (int w = 0; w < 8; ++w) s += sPart[w][tid];
                out[eg] = s;
            }
        }
    }
}

extern "C" void kernel_launch(void* const* d_in, const int* in_sizes, int n_in,
                              void* d_out, int out_size, void* d_ws, size_t ws_size,
                              hipStream_t stream) {
    const float* zd = (const float*)d_in[0];
    const float* zp = (const float*)d_in[1];
    const int*   eli = (const int*)d_in[2];
    const float* W1 = (const float*)d_in[3];
    const float* b1 = (const float*)d_in[4];
    const float* W2 = (const float*)d_in[5];
    const float* b2 = (const float*)d_in[6];
    float* out = (float*)d_out;

    const int E  = in_sizes[2] / 2;
    const int nd = in_sizes[0];        // N_DRUG * 128
    const int np = in_sizes[1];        // N_PROT * 128
    const int Nd = nd / 128, Np = np / 128;
    const int nbd = (Nd + 31) / 32, nbp = (Np + 31) / 32;   // 32-row tiles

    // ws layout: Hd u8 | Hp u8 | scD f32 | scP f32
    const size_t offHp = (size_t)Nd * 128;
    const size_t offSd = (offHp + (size_t)Np * 128 + 15) & ~(size_t)15;
    const size_t offSp = offSd + (size_t)Nd * sizeof(float);
    const size_t need  = offSp + (size_t)Np * sizeof(float);

    if (ws_size >= need) {
        unsigned char* Hd = (unsigned char*)d_ws;
        unsigned char* Hp = Hd + offHp;
        float* scD = (float*)((char*)d_ws + offSd);
        float* scP = (float*)((char*)d_ws + offSp);
        hipLaunchKernelGGL(hprepq_kernel, dim3(nbd + nbp), dim3(256), 0, stream,
                           zd, zp, W1, b1, Hd, Hp, scD, scP, Nd, Np, nbd);
        hipLaunchKernelGGL(edgeq_kernel, dim3(4096), dim3(256), 0, stream,
                           Hd, Hp, scD, scP, eli, W2, b2, out, E);
    } else {
        const int nTiles = (E + TE - 1) / TE;
        hipLaunchKernelGGL(ec_fallback, dim3(2048), dim3(512), 0, stream,
                           zd, zp, eli, W1, b1, W2, b2, out, E, nTiles);
    }
}

// Round 14
// 57.961 us; speedup vs baseline: 1.1389x; 1.1389x over previous
//
#include <hip/hip_runtime.h>

// EdgeClassifier:
//   Hd = q8(zd @ W1[:, :128]^T + b1), per-row scale, stored BIASED (int8 xor 0x80)
//   Hp = q8(zp @ W1[:, 128:]^T),      per-row scale, biased
//   out[e] = W2 . relu(Hd[row]*sd + Hp[col]*sp) + b2
// R14: exact revert to R10 (best measured: 57.9us total; edgeq ~37.8, hprepq ~19).
// R11/R12/R13 variations (deeper MLP @ lower occupancy, 4-wave hprep, 32-row hprep)
// all measured worse; this is the empirical optimum configuration.

typedef __attribute__((ext_vector_type(8))) short bhalf8;
typedef __attribute__((ext_vector_type(4))) float f32x4;
typedef _Float16 half2_t __attribute__((ext_vector_type(2)));

__device__ __forceinline__ unsigned bfr(float f) {
    unsigned u = __builtin_bit_cast(unsigned, f);
    return (u + 0x7fffu + ((u >> 16) & 1u)) >> 16;
}
__device__ __forceinline__ unsigned pk2(float a, float b) {
    return bfr(a) | (bfr(b) << 16);
}

#define SH_STRIDE 132   // fp32 elems; 528B rows: 16B-aligned, <=4-way LDS conflicts

// ---------- K1: H-prep GEMM + per-row quantize to biased uint8 ----------
__global__ __launch_bounds__(512) void hprepq_kernel(
    const float* __restrict__ zd, const float* __restrict__ zp,
    const float* __restrict__ W1, const float* __restrict__ b1,
    unsigned char* __restrict__ Hd, unsigned char* __restrict__ Hp,
    float* __restrict__ scD, float* __restrict__ scP,
    int Nd, int Np, int nbd)
{
    __shared__ __align__(16) char smem[64 * SH_STRIDE * 4];   // 33.8 KB
    short* sZ = (short*)smem;          // staging view (16 KB, XOR-swizzled)
    float* sH = (float*)smem;          // h-transpose view (stride SH_STRIDE)

    const bool isP = (int)blockIdx.x >= nbd;
    const float* z = isP ? zp : zd;
    unsigned char* H = isP ? Hp : Hd;
    float* sc = isP ? scP : scD;
    const int N    = isP ? Np : Nd;
    const int koff = isP ? 128 : 0;
    const int blk  = isP ? blockIdx.x - nbd : blockIdx.x;

    const int tid  = threadIdx.x;
    const int wave = tid >> 6;
    const int lane = tid & 63;
    const int l15  = lane & 15;
    const int lhi  = lane >> 4;
    const int ocol = wave * 16 + l15;

    bhalf8 bfrag[4];
    #pragma unroll
    for (int ks = 0; ks < 4; ++ks) {
        const float4* src = (const float4*)(W1 + ocol * 256 + koff + ks * 32 + lhi * 8);
        float4 p = src[0], q = src[1];
        bhalf8 f;
        f[0] = (short)bfr(p.x); f[1] = (short)bfr(p.y);
        f[2] = (short)bfr(p.z); f[3] = (short)bfr(p.w);
        f[4] = (short)bfr(q.x); f[5] = (short)bfr(q.y);
        f[6] = (short)bfr(q.z); f[7] = (short)bfr(q.w);
        bfrag[ks] = f;
    }
    const float bias = isP ? 0.0f : b1[ocol];
    const int r0 = blk * 64;

    {
        const int rl = tid >> 3;
        const int grow = min(r0 + rl, N - 1);
        const float4* zr = (const float4*)(z + (size_t)grow * 128);
        #pragma unroll
        for (int q = 0; q < 4; ++q) {
            const int s = (tid & 7) + q * 8;
            float4 v = zr[s];
            uint2 w; w.x = pk2(v.x, v.y); w.y = pk2(v.z, v.w);
            int byte = (rl * 256 + s * 8) ^ ((rl & 7) << 4);
            *(uint2*)((char*)sZ + byte) = w;
        }
    }
    __syncthreads();

    f32x4 acc[4] = {{0.f,0.f,0.f,0.f},{0.f,0.f,0.f,0.f},
                    {0.f,0.f,0.f,0.f},{0.f,0.f,0.f,0.f}};
    #pragma unroll
    for (int ks = 0; ks < 4; ++ks) {
        #pragma unroll
        for (int rt = 0; rt < 4; ++rt) {
            const int row = rt * 16 + l15;
            int byte = (row * 256 + ks * 64 + lhi * 16) ^ ((row & 7) << 4);
            bhalf8 af = *(const bhalf8*)((const char*)sZ + byte);
            acc[rt] = __builtin_amdgcn_mfma_f32_16x16x32_bf16(af, bfrag[ks], acc[rt], 0, 0, 0);
        }
    }
    __syncthreads();   // done reading sZ; smem becomes sH

    #pragma unroll
    for (int rt = 0; rt < 4; ++rt) {
        #pragma unroll
        for (int i = 0; i < 4; ++i) {
            const int row = rt * 16 + lhi * 4 + i;
            sH[row * SH_STRIDE + ocol] = acc[rt][i] + bias;
        }
    }
    __syncthreads();

    {
        const int qrow = tid >> 3;
        const int k    = tid & 7;
        float4 v4[4];
        float mx = 0.0f;
        #pragma unroll
        for (int j = 0; j < 4; ++j) {
            v4[j] = *(const float4*)(sH + qrow * SH_STRIDE + k * 16 + j * 4);
            mx = fmaxf(mx, fmaxf(fmaxf(fabsf(v4[j].x), fabsf(v4[j].y)),
                                 fmaxf(fabsf(v4[j].z), fabsf(v4[j].w))));
        }
        mx = fmaxf(mx, __shfl_xor(mx, 1, 64));
        mx = fmaxf(mx, __shfl_xor(mx, 2, 64));
        mx = fmaxf(mx, __shfl_xor(mx, 4, 64));
        const float inv = 127.0f / fmaxf(mx, 1e-20f);
        uint4 o;
        unsigned ob[4];
        #pragma unroll
        for (int j = 0; j < 4; ++j) {
            int a0 = __float2int_rn(v4[j].x * inv);
            int a1 = __float2int_rn(v4[j].y * inv);
            int a2 = __float2int_rn(v4[j].z * inv);
            int a3 = __float2int_rn(v4[j].w * inv);
            ob[j] = ((unsigned)(a0 & 0xff) | ((unsigned)(a1 & 0xff) << 8) |
                     ((unsigned)(a2 & 0xff) << 16) | ((unsigned)(a3 & 0xff) << 24))
                    ^ 0x80808080u;                     // bias to uint8
        }
        o.x = ob[0]; o.y = ob[1]; o.z = ob[2]; o.w = ob[3];
        const int grow = r0 + qrow;
        if (grow < N) {
            *(uint4*)(H + (size_t)grow * 128 + k * 16) = o;
            if (k == 0) sc[grow] = mx * (1.0f / 127.0f);
        }
    }
}

// ---------- K2: per-edge gather + packed-f16 dequant/relu/dot ----------
// 8 lanes/edge, uint4 (16 bytes) per lane per table; 4 edges/group/iter
__global__ __launch_bounds__(256, 4) void edgeq_kernel(
    const unsigned char* __restrict__ Hd, const unsigned char* __restrict__ Hp,
    const float* __restrict__ scD, const float* __restrict__ scP,
    const int* __restrict__ eli, const float* __restrict__ W2,
    const float* __restrict__ b2, float* __restrict__ out, int E)
{
    const int sub = threadIdx.x & 7;
    const int grp = threadIdx.x >> 3;                // 0..31
    // W2 slice for elems sub*16 .. sub*16+15, as 8 f16 pairs
    half2_t w2h[8];
    #pragma unroll
    for (int j = 0; j < 8; ++j) {
        float2 w = ((const float2*)W2)[sub * 8 + j];
        w2h[j][0] = (_Float16)w.x; w2h[j][1] = (_Float16)w.y;
    }
    const float b2v = b2[0];
    const half2_t c1152 = { (_Float16)1152.0f, (_Float16)1152.0f };

    const int EPB = 32 * 4;                          // 128 edges per block-iter
    const int step = gridDim.x * EPB;
    int base = blockIdx.x * EPB;
    if (base >= E) return;

    int row[4], col[4];
    #pragma unroll
    for (int u = 0; u < 4; ++u) {
        const int e = base + grp * 4 + u;
        row[u] = (e < E) ? eli[e] : 0;
        col[u] = (e < E) ? eli[E + e] : 0;
    }

    for (; base < E; base += step) {
        uint4 qd[4], qp[4];
        float sdc[4], r[4];
        #pragma unroll
        for (int u = 0; u < 4; ++u) {
            qd[u] = *(const uint4*)(Hd + (size_t)row[u] * 128 + sub * 16);
            qp[u] = *(const uint4*)(Hp + (size_t)col[u] * 128 + sub * 16);
            const float sd = scD[row[u]];
            const float sp = scP[col[u]];
            sdc[u] = fmaxf(sd, 1e-25f);
            r[u]   = sp * __builtin_amdgcn_rcpf(sdc[u]);
        }
        const int nb = base + step;
        if (nb < E) {
            #pragma unroll
            for (int u = 0; u < 4; ++u) {
                const int e = nb + grp * 4 + u;
                row[u] = (e < E) ? eli[e] : 0;
                col[u] = (e < E) ? eli[E + e] : 0;
            }
        }
        #pragma unroll
        for (int u = 0; u < 4; ++u) {
            const _Float16 rh = (_Float16)r[u];
            const half2_t ru2 = { rh, rh };
            float s = 0.f;
            const unsigned dws[4] = {qd[u].x, qd[u].y, qd[u].z, qd[u].w};
            const unsigned pws[4] = {qp[u].x, qp[u].y, qp[u].z, qp[u].w};
            #pragma unroll
            for (int j = 0; j < 4; ++j) {
                const unsigned dw = dws[j], pw = pws[j];
                // lo pair: bytes 0,1 ; hi pair: bytes 2,3 -> f16 (1024+b)
                half2_t d0 = __builtin_bit_cast(half2_t,
                    __builtin_amdgcn_perm(0x64646464u, dw, 0x04010400u)) - c1152;
                half2_t d1 = __builtin_bit_cast(half2_t,
                    __builtin_amdgcn_perm(0x64646464u, dw, 0x04030402u)) - c1152;
                half2_t p0 = __builtin_bit_cast(half2_t,
                    __builtin_amdgcn_perm(0x64646464u, pw, 0x04010400u)) - c1152;
                half2_t p1 = __builtin_bit_cast(half2_t,
                    __builtin_amdgcn_perm(0x64646464u, pw, 0x04030402u)) - c1152;
                half2_t t0 = __builtin_elementwise_max(
                    __builtin_elementwise_fma(ru2, p0, d0), (half2_t){0, 0});
                half2_t t1 = __builtin_elementwise_max(
                    __builtin_elementwise_fma(ru2, p1, d1), (half2_t){0, 0});
                s = __builtin_amdgcn_fdot2(t0, w2h[j * 2],     s, false);
                s = __builtin_amdgcn_fdot2(t1, w2h[j * 2 + 1], s, false);
            }
            s += __shfl_xor(s, 1, 64);
            s += __shfl_xor(s, 2, 64);
            s += __shfl_xor(s, 4, 64);
            const int e = base + grp * 4 + u;
            if (sub == 0 && e < E) out[e] = fmaf(s, sdc[u], b2v);
        }
    }
}

// ---------- last-resort fallback: proven R1 kernel ----------
#define TE 64
__global__ __launch_bounds__(512, 4) void ec_fallback(
    const float* __restrict__ zd, const float* __restrict__ zp,
    const int* __restrict__ eli, const float* __restrict__ W1,
    const float* __restrict__ b1, const float* __restrict__ W2,
    const float* __restrict__ b2, float* __restrict__ out,
    int E, int nTiles)
{
    __shared__ __align__(16) short sZ[TE * 256];
    __shared__ float sPart[8][TE];
    const int tid  = threadIdx.x;
    const int wave = tid >> 6;
    const int lane = tid & 63;
    const int l15  = lane & 15;
    const int lhi  = lane >> 4;
    const int ocol = wave * 16 + l15;
    bhalf8 bfrag[8];
    #pragma unroll
    for (int ks = 0; ks < 8; ++ks) {
        const float4* src = (const float4*)(W1 + ocol * 256 + ks * 32 + lhi * 8);
        float4 p = src[0], q = src[1];
        bhalf8 f;
        f[0] = (short)bfr(p.x); f[1] = (short)bfr(p.y);
        f[2] = (short)bfr(p.z); f[3] = (short)bfr(p.w);
        f[4] = (short)bfr(q.x); f[5] = (short)bfr(q.y);
        f[6] = (short)bfr(q.z); f[7] = (short)bfr(q.w);
        bfrag[ks] = f;
    }
    const float b1v = b1[ocol];
    const float w2v = W2[ocol];
    const float b2v = b2[0];
    const int slot = tid >> 5;
    const int lane32 = tid & 31;
    for (int tile = blockIdx.x; tile < nTiles; tile += gridDim.x) {
        const int base = tile * TE;
        __syncthreads();
        #pragma unroll
        for (int r = 0; r < 4; ++r) {
            const int e  = slot * 4 + r;
            const int eg = base + e;
            int drow = 0, pcol = 0;
            if (eg < E) { drow = eli[eg]; pcol = eli[E + eg]; }
            float4 v = ((const float4*)(zd + (size_t)drow * 128))[lane32];
            float4 u = ((const float4*)(zp + (size_t)pcol * 128))[lane32];
            int byte0 = (e * 512 + lane32 * 8) ^ ((e & 7) << 4);
            uint2 pv; pv.x = pk2(v.x, v.y); pv.y = pk2(v.z, v.w);
            *(uint2*)((char*)sZ + byte0) = pv;
            int byte1 = (e * 512 + 256 + lane32 * 8) ^ ((e & 7) << 4);
            uint2 pu; pu.x = pk2(u.x, u.y); pu.y = pk2(u.z, u.w);
            *(uint2*)((char*)sZ + byte1) = pu;
        }
        __syncthreads();
        f32x4 acc[4] = {{0.f,0.f,0.f,0.f},{0.f,0.f,0.f,0.f},
                        {0.f,0.f,0.f,0.f},{0.f,0.f,0.f,0.f}};
        #pragma unroll
        for (int ks = 0; ks < 8; ++ks) {
            const int kb = (ks * 32 + lhi * 8) * 2;
            #pragma unroll
            for (int rt = 0; rt < 4; ++rt) {
                const int row = rt * 16 + l15;
                int byte = (row * 512 + kb) ^ ((row & 7) << 4);
                bhalf8 af = *(const bhalf8*)((const char*)sZ + byte);
                acc[rt] = __builtin_amdgcn_mfma_f32_16x16x32_bf16(af, bfrag[ks], acc[rt], 0, 0, 0);
            }
        }
        #pragma unroll
        for (int rt = 0; rt < 4; ++rt) {
            #pragma unroll
            for (int i = 0; i < 4; ++i) {
                float v = acc[rt][i] + b1v;
                v = fmaxf(v, 0.0f) * w2v;
                v += __shfl_xor(v, 1, 64);
                v += __shfl_xor(v, 2, 64);
                v += __shfl_xor(v, 4, 64);
                v += __shfl_xor(v, 8, 64);
                if (l15 == 0) sPart[wave][rt * 16 + lhi * 4 + i] = v;
            }
        }
        __syncthreads();
        if (tid < TE) {
            const int eg = base + tid;
            if (eg < E) {
                float s = b2v;
                #pragma unroll
                for (int w = 0; w < 8; ++w) s += sPart[w][tid];
                out[eg] = s;
            }
        }
    }
}

extern "C" void kernel_launch(void* const* d_in, const int* in_sizes, int n_in,
                              void* d_out, int out_size, void* d_ws, size_t ws_size,
                              hipStream_t stream) {
    const float* zd = (const float*)d_in[0];
    const float* zp = (const float*)d_in[1];
    const int*   eli = (const int*)d_in[2];
    const float* W1 = (const float*)d_in[3];
    const float* b1 = (const float*)d_in[4];
    const float* W2 = (const float*)d_in[5];
    const float* b2 = (const float*)d_in[6];
    float* out = (float*)d_out;

    const int E  = in_sizes[2] / 2;
    const int nd = in_sizes[0];        // N_DRUG * 128
    const int np = in_sizes[1];        // N_PROT * 128
    const int Nd = nd / 128, Np = np / 128;
    const int nbd = (Nd + 63) / 64, nbp = (Np + 63) / 64;

    // ws layout: Hd u8 | Hp u8 | scD f32 | scP f32
    const size_t offHp = (size_t)Nd * 128;
    const size_t offSd = (offHp + (size_t)Np * 128 + 15) & ~(size_t)15;
    const size_t offSp = offSd + (size_t)Nd * sizeof(float);
    const size_t need  = offSp + (size_t)Np * sizeof(float);

    if (ws_size >= need) {
        unsigned char* Hd = (unsigned char*)d_ws;
        unsigned char* Hp = Hd + offHp;
        float* scD = (float*)((char*)d_ws + offSd);
        float* scP = (float*)((char*)d_ws + offSp);
        hipLaunchKernelGGL(hprepq_kernel, dim3(nbd + nbp), dim3(512), 0, stream,
                           zd, zp, W1, b1, Hd, Hp, scD, scP, Nd, Np, nbd);
        hipLaunchKernelGGL(edgeq_kernel, dim3(4096), dim3(256), 0, stream,
                           Hd, Hp, scD, scP, eli, W2, b2, out, E);
    } else {
        const int nTiles = (E + TE - 1) / TE;
        hipLaunchKernelGGL(ec_fallback, dim3(2048), dim3(512), 0, stream,
                           zd, zp, eli, W1, b1, W2, b2, out, E, nTiles);
    }
}